// Round 11
// baseline (297.297 us; speedup 1.0000x reference)
//
#include <hip/hip_runtime.h>
#include <math.h>

// FactorizationMachine: out = sigmoid( X@fc_w + fc_b + 0.5*( sum_d (X@w)_d^2 - (X^2)@g ) )
//
// R10 diagnosis: three independent designs (R0/R4, R5, R9) converge at ~290 us
// with measured HBM fetch <= 836 MB (~2.8 TB/s) while fillBuffer hits 6.6 TB/s.
// Shared invariant: W loaded at lane-stride 256 B -> 64 cache lines per
// instruction -> ~1168 L1 line-transactions per wave-iter (~191 us of L1/TA
// time at 1 line/cyc/CU). Fix: read W through the TRANSPOSED layout (wT[d][f],
// phase 0) so every load is lane-coalesced (16 lines/instr): 416 lines/iter.
//  - Phase 1 keeps R9's proven geometry: 512 thr = 8 waves x 8 rows = 64
//    rows/block (ideal HBM bytes, R8-measured), KSPLIT=4 -> 256 blocks = 1/CU,
//    R4's hoisted 2-batch schedule (wt in two 8-reg batches, ~230 VGPR).
//  - gneg[f] precomputed -> no per-feature g recompute (-25% VALU).
//  - Phase 2: combine 4 chunk-partials + sigmoid (validated absmax <= 2e-9).

constexpr int B_ROWS  = 4096;
constexpr int F_FEAT  = 50000;
constexpr int NF4     = F_FEAT / 4;        // 12500
constexpr int D_FAC   = 16;
constexpr int TPB     = 512;
constexpr int WPB     = 8;                 // waves per block
constexpr int ROWS    = 8;                 // rows per wave
constexpr int RB      = WPB * ROWS;        // 64 rows per block
constexpr int NGRP    = B_ROWS / RB;       // 64 row-groups
constexpr int KSPLIT  = 4;
constexpr int CHUNK   = NF4 / KSPLIT;      // 3125
constexpr int NBLK    = NGRP * KSPLIT;     // 256 blocks (1 per CU)
constexpr int NVAL    = ROWS * (D_FAC + 1);// 136 partials per wave

constexpr size_t WT_OFF = 0;                       // wT: 16 * 50000 floats
constexpr size_t G_OFF  = (size_t)D_FAC * F_FEAT;  // gneg: 50000 floats
constexpr size_t P_OFF  = G_OFF + F_FEAT;          // partials

typedef float f32x4 __attribute__((ext_vector_type(4)));

// ---------------- Phase 0: W transpose + gneg (validated R6/R7) ----------------
__global__ __launch_bounds__(256)
void fm_prep(const float* __restrict__ W, float* __restrict__ ws)
{
    const int f = blockIdx.x * 256 + threadIdx.x;
    if (f >= F_FEAT) return;
    const f32x4* W4 = reinterpret_cast<const f32x4*>(W);
    f32x4 wv[4];
#pragma unroll
    for (int q = 0; q < 4; ++q) wv[q] = W4[(size_t)f * 4 + q];
    float gs = 0.f;
#pragma unroll
    for (int t = 0; t < D_FAC; ++t) {
        const float wd = wv[t >> 2][t & 3];
        gs = fmaf(wd, wd, gs);
        ws[WT_OFF + (size_t)t * F_FEAT + f] = wd;   // coalesced per t
    }
    ws[G_OFF + f] = -0.5f * gs;
}

// ---------------- Phase 1: main sweep ----------------
__global__ __launch_bounds__(TPB, 2)   // 8 waves/CU (one block), VGPR cap 256
void fm_main(const float* __restrict__ X,
             const float* __restrict__ fcw,
             const float* __restrict__ wt,     // ws + WT_OFF
             const float* __restrict__ gneg,   // ws + G_OFF
             float* __restrict__ pout)         // ws + P_OFF
{
    const int tid  = threadIdx.x;
    const int lane = tid & 63;
    const int wid  = tid >> 6;             // 0..7, wave-uniform
    const int c    = blockIdx.x & (KSPLIT - 1);
    const int grp  = blockIdx.x >> 2;
    const int row0 = grp * RB + wid * ROWS;
    const int beg  = c * CHUNK;
    const int end  = beg + CHUNK;

    const f32x4* X4  = reinterpret_cast<const f32x4*>(X);
    const f32x4* WT4 = reinterpret_cast<const f32x4*>(wt);
    const f32x4* FW4 = reinterpret_cast<const f32x4*>(fcw);
    const f32x4* G4  = reinterpret_cast<const f32x4*>(gneg);

    float s[ROWS][D_FAC];                  // 128 acc
    float lin[ROWS];                       // 8  (linear + sum_sq correction fused)
#pragma unroll
    for (int r = 0; r < ROWS; ++r) {
        lin[r] = 0.f;
#pragma unroll
        for (int t = 0; t < D_FAC; ++t) s[r][t] = 0.f;
    }

    for (int f4 = beg + lane; f4 < end; f4 += 64) {
        // 8 coalesced X streams (16 lines/instr)
        f32x4 xv[ROWS];
#pragma unroll
        for (int r = 0; r < ROWS; ++r)
            xv[r] = X4[(size_t)(row0 + r) * NF4 + f4];

        const f32x4 fw = FW4[f4];
        const f32x4 gn = G4[f4];

        // wT batch 1: factors d=0..7, lane-coalesced (16 lines/instr)
        f32x4 wtb[8];
#pragma unroll
        for (int d = 0; d < 8; ++d)
            wtb[d] = WT4[(size_t)d * NF4 + f4];

#pragma unroll
        for (int j = 0; j < 4; ++j) {
#pragma unroll
            for (int r = 0; r < ROWS; ++r) {
                const float x = xv[r][j];
#pragma unroll
                for (int d = 0; d < 8; ++d)
                    s[r][d] = fmaf(x, wtb[d][j], s[r][d]);
            }
        }

        // wT batch 2: factors d=8..15 (same 8 registers)
#pragma unroll
        for (int d = 0; d < 8; ++d)
            wtb[d] = WT4[(size_t)(8 + d) * NF4 + f4];

#pragma unroll
        for (int j = 0; j < 4; ++j) {
            const float fwj = fw[j];
            const float gnj = gn[j];
#pragma unroll
            for (int r = 0; r < ROWS; ++r) {
                const float x  = xv[r][j];
#pragma unroll
                for (int d = 0; d < 8; ++d)
                    s[r][8 + d] = fmaf(x, wtb[d][j], s[r][8 + d]);
                lin[r] = fmaf(x, fwj, lin[r]);
                lin[r] = fmaf(x * x, gnj, lin[r]);
            }
        }
    }

    // ---- per-wave butterfly reduce of 136 values; value i -> lane i&63 ----
    float keep0 = 0.f, keep1 = 0.f, keep2 = 0.f;
    int idx = 0;
#pragma unroll
    for (int r = 0; r < ROWS; ++r) {
#pragma unroll
        for (int t = 0; t <= D_FAC; ++t) {
            float v = (t < D_FAC) ? s[r][t] : lin[r];
#pragma unroll
            for (int m = 32; m >= 1; m >>= 1) v += __shfl_xor(v, m, 64);
            if (idx < 64)       { if (lane == idx)        keep0 = v; }
            else if (idx < 128) { if (lane == idx - 64)   keep1 = v; }
            else                { if (lane == idx - 128)  keep2 = v; }
            ++idx;
        }
    }
    float* base = pout + ((size_t)blockIdx.x * WPB + wid) * NVAL;
    base[lane] = keep0;
    base[64 + lane] = keep1;
    if (lane < NVAL - 128) base[128 + lane] = keep2;
}

// ---------------- Phase 2: combine chunks + sigmoid ----------------
__global__ __launch_bounds__(256)
void fm_final(const float* __restrict__ pout,
              const float* __restrict__ fcb,
              float* __restrict__ out)
{
    const int r = blockIdx.x * 256 + threadIdx.x;
    if (r >= B_ROWS) return;
    const int grp = r >> 6;                // row-group of 64
    const int rr  = r & 63;
    const int wid = rr >> 3;               // wave within block
    const int rw  = rr & 7;                // row within wave

    float acc[D_FAC + 1];
#pragma unroll
    for (int t = 0; t <= D_FAC; ++t) acc[t] = 0.f;

#pragma unroll
    for (int c = 0; c < KSPLIT; ++c) {
        const float* p = pout
            + ((size_t)((grp * KSPLIT + c) * WPB + wid)) * NVAL + rw * (D_FAC + 1);
#pragma unroll
        for (int t = 0; t <= D_FAC; ++t) acc[t] += p[t];
    }

    float ss = 0.f;
#pragma unroll
    for (int t = 0; t < D_FAC; ++t) ss = fmaf(acc[t], acc[t], ss);

    const float logit = acc[D_FAC] + fcb[0] + 0.5f * ss;
    out[r] = 1.0f / (1.0f + expf(-logit));
}

extern "C" void kernel_launch(void* const* d_in, const int* in_sizes, int n_in,
                              void* d_out, int out_size, void* d_ws, size_t ws_size,
                              hipStream_t stream)
{
    const float* X   = (const float*)d_in[0];
    const float* fcw = (const float*)d_in[1];
    const float* fcb = (const float*)d_in[2];
    const float* W   = (const float*)d_in[3];
    float* out = (float*)d_out;
    float* ws  = (float*)d_ws;   // ~4.5 MB used

    hipLaunchKernelGGL(fm_prep, dim3((F_FEAT + 255) / 256), dim3(256), 0, stream,
                       W, ws);
    hipLaunchKernelGGL(fm_main, dim3(NBLK), dim3(TPB), 0, stream,
                       X, fcw, ws + WT_OFF, ws + G_OFF, ws + P_OFF);
    hipLaunchKernelGGL(fm_final, dim3((B_ROWS + 255) / 256), dim3(256), 0, stream,
                       ws + P_OFF, fcb, out);
}